// Round 11
// baseline (440.421 us; speedup 1.0000x reference)
//
// Resubmit #2 of round-8 occupancy kernel (two infra failures, zero bench signal).
#include <hip/hip_runtime.h>

#define BB   64
#define SS   1024
#define HH   256
#define OUTD 768
#define TT   16
#define DOUT 512
#define DIN  512

typedef __attribute__((ext_vector_type(8))) short short8;
typedef __attribute__((ext_vector_type(4))) short short4v;
typedef __attribute__((ext_vector_type(4))) float f32x4;

__device__ __forceinline__ unsigned short f2bf(float f) {
    unsigned u = __builtin_bit_cast(unsigned, f);
    u += 0x7FFFu + ((u >> 16) & 1u);
    return (unsigned short)(u >> 16);
}
__device__ __forceinline__ float bf2f(unsigned short h) {
    unsigned u = ((unsigned)h) << 16;
    return __builtin_bit_cast(float, u);
}

// ---------------------------------------------------------------------------
struct CellDesc {
    const unsigned short* Wr;        // [strip128][plane2][step32][nh2][lane64][8]
    const float* bias;
    const unsigned short *uHi, *uLo;
    const unsigned short *hPrevHi, *hPrevLo, *hDelHi, *hDelLo;
    const float *cPrev, *cDel;
    float* cOut;
    unsigned short *outHi, *outLo;
    float* f32out;
    const float* resid;
    unsigned short *hHi, *hLo;
    int Ku, Kin, prev_ok, delayed_ok, nst32, pad;
};
struct StepArgs { CellDesc c[4]; };

// ---------------------------------------------------------------------------
// Tiled wavefront cell kernel. grid = nCells*128 blocks x 256 thr (4 waves).
// Block (cell, strip): output tile = 64 rows x (8 state cols x 4 gates = 32 n).
// Waves (wm 2 x wh 2): wave = 32 rows x 16 n-cols.
// LDS ~62 KB -> 2 blocks/CU co-resident (barrier drains overlap across blocks).
// K-loop: BK=64/step, A+W double-buffered, 1 barrier/step, 12 MFMA/wave/step.
// ---------------------------------------------------------------------------
__global__ __launch_bounds__(256, 2) void cell_wave(StepArgs sa)
{
    __shared__ unsigned short Alds[2][2 * 64 * 72];   // [buf][pl*4608 + row*72 + k]
    __shared__ unsigned short Wlds[2][2 * 2048];      // [buf][pl*2048 + ((kk*2+nh)*64+l)*8]
    __shared__ float Csum[32 * 68];                   // [n][row]

    const int cellIdx = blockIdx.x >> 7;
    const int strip   = blockIdx.x & 127;
    const CellDesc& a = sa.c[cellIdx];

    const int tid  = threadIdx.x;
    const int lane = tid & 63;
    const int w    = tid >> 6;        // 0..3
    const int wm   = w >> 1;          // row half
    const int wh   = w & 1;           // n half
    const int l15  = lane & 15;
    const int lk8  = (lane >> 4) * 8;

    const int Ku    = a.Ku;
    const int nst32 = a.nst32;
    const int nst64 = (a.prev_ok ? a.Kin : a.Ku) >> 6;

    // staging maps (constant per thread)
    const int wkk = tid >> 7, wnh = (tid >> 6) & 1, wl = tid & 63;

    f32x4 rA[2][2], rW[2];
    auto stageLoad = [&](int S) {
        const int kb = S * 64;
        const unsigned short *sHi, *sLo; int stride, koff;
        if (kb < Ku)           { sHi = a.uHi;     sLo = a.uLo;     stride = Ku; koff = kb; }
        else if (kb < Ku + HH) { sHi = a.hPrevHi; sLo = a.hPrevLo; stride = HH; koff = kb - Ku; }
        else                   { sHi = a.hDelHi;  sLo = a.hDelLo;  stride = HH; koff = kb - Ku - HH; }
        #pragma unroll
        for (int i = 0; i < 2; ++i) {
            const int e = i * 256 + tid;
            const int row = e >> 3, oct = e & 7;
            rA[0][i] = *(const f32x4*)(sHi + (size_t)row * stride + koff + oct * 8);
            rA[1][i] = *(const f32x4*)(sLo + (size_t)row * stride + koff + oct * 8);
        }
        #pragma unroll
        for (int pl = 0; pl < 2; ++pl) {
            const size_t wb = ((((size_t)strip * 2 + pl) * nst32 + (2 * S + wkk)) * 2 + wnh) * 512
                              + (size_t)wl * 8;
            rW[pl] = *(const f32x4*)(a.Wr + wb);
        }
    };
    auto stageWrite = [&](int nb) {
        #pragma unroll
        for (int i = 0; i < 2; ++i) {
            const int e = i * 256 + tid;
            const int row = e >> 3, oct = e & 7;
            *(f32x4*)&Alds[nb][row * 72 + oct * 8]        = rA[0][i];
            *(f32x4*)&Alds[nb][4608 + row * 72 + oct * 8] = rA[1][i];
        }
        *(f32x4*)&Wlds[nb][tid * 8]        = rW[0];
        *(f32x4*)&Wlds[nb][2048 + tid * 8] = rW[1];
    };

    f32x4 acc[2] = {{0,0,0,0},{0,0,0,0}};

    stageLoad(0);
    stageWrite(0);
    __syncthreads();

    int cur = 0;
    for (int S = 0; S < nst64; ++S) {
        const bool more = (S + 1 < nst64);
        if (more) stageLoad(S + 1);

        #pragma unroll
        for (int kk = 0; kk < 2; ++kk) {
            short8 whi = *(const short8*)&Wlds[cur][((kk * 2 + wh) * 64 + lane) * 8];
            short8 wlo = *(const short8*)&Wlds[cur][2048 + ((kk * 2 + wh) * 64 + lane) * 8];
            #pragma unroll
            for (int mm = 0; mm < 2; ++mm) {
                const int row = wm * 32 + mm * 16 + l15;
                short8 ahi = *(const short8*)&Alds[cur][row * 72 + kk * 32 + lk8];
                short8 alo = *(const short8*)&Alds[cur][4608 + row * 72 + kk * 32 + lk8];
                acc[mm] = __builtin_amdgcn_mfma_f32_16x16x32_bf16(ahi, whi, acc[mm], 0, 0, 0);
                acc[mm] = __builtin_amdgcn_mfma_f32_16x16x32_bf16(alo, whi, acc[mm], 0, 0, 0);
                acc[mm] = __builtin_amdgcn_mfma_f32_16x16x32_bf16(ahi, wlo, acc[mm], 0, 0, 0);
            }
        }
        if (more) stageWrite(cur ^ 1);
        __syncthreads();
        cur ^= 1;
    }

    // C frags -> Csum  (col c=lane&15 -> n = wh*16+c; row = wm*32+mm*16+(lane>>4)*4+i)
    {
        const int c  = lane & 15;
        const int r4 = (lane >> 4) * 4;
        #pragma unroll
        for (int mm = 0; mm < 2; ++mm)
            *(f32x4*)&Csum[(wh * 16 + c) * 68 + wm * 32 + mm * 16 + r4] = acc[mm];
    }
    __syncthreads();

    // block-local LSTM epilogue: 64 rows x 8 state cols, 2 per thread
    // n = g*8 + jj  (g = gate)
    #pragma unroll
    for (int e2 = 0; e2 < 2; ++e2) {
        const int idx = tid + e2 * 256;
        const int r   = idx >> 3;
        const int jj  = idx & 7;
        const int j   = strip * 8 + jj;
        float g0 = Csum[(0  + jj) * 68 + r] + a.bias[j];
        float g1 = Csum[(8  + jj) * 68 + r] + a.bias[SS + j];
        float g2 = Csum[(16 + jj) * 68 + r] + a.bias[2 * SS + j];
        float g3 = Csum[(24 + jj) * 68 + r] + a.bias[3 * SS + j];

        float f  = 1.f / (1.f + __expf(-(g0 + 1.f)));
        float n  = tanhf(g1);
        float av = 1.f / (1.f + __expf(-g2));
        float o  = 1.f / (1.f + __expf(-g3));

        float pC = a.prev_ok ? a.cPrev[(size_t)r * SS + j] : 0.f;
        float dC = a.delayed_ok ? a.cDel[(size_t)r * SS + j] : pC;
        float wC = a.delayed_ok ? (av * pC + (1.f - av) * dC) : pC;
        float nf = a.prev_ok ? (f * wC + (1.f - f) * n) : n;
        float wh2 = o * nf;

        a.cOut[(size_t)r * SS + j] = nf;

        if (j < OUTD) {
            float v = wh2;
            const size_t oidx = (size_t)r * OUTD + j;
            if (a.resid)  v += a.resid[oidx];
            if (a.f32out) a.f32out[oidx] = v;
            unsigned short hb = f2bf(v);
            a.outHi[oidx] = hb;
            a.outLo[oidx] = f2bf(v - bf2f(hb));
        } else {
            const int jo = j - OUTD;
            const size_t hidx = (size_t)r * HH + jo;
            unsigned short hb = f2bf(wh2);
            a.hHi[hidx] = hb;
            a.hLo[hidx] = f2bf(wh2 - bf2f(hb));
        }
    }
}

// ---------------------------------------------------------------------------
// W reorder: fp32 [4096][Kin] -> bf16 hi/lo fragment-linear:
// [strip128][plane2][step32][nh2][lane64][8]
// n = nh*16 + (l&15); g = n>>3; jj = n&7; W row = g*1024 + strip*8 + jj;
// k = step*32 + (l>>4)*8 + q4.
// ---------------------------------------------------------------------------
__global__ __launch_bounds__(256) void prep_reorderW(
    const float* __restrict__ W, int Kin, int nst32,
    unsigned short* __restrict__ Wr)
{
    const int strip = blockIdx.x;     // 0..127
    const int step  = blockIdx.y;     // 0..nst32-1
    const int t     = threadIdx.x;
    const int q4    = (t >> 7) * 4;   // 0 or 4
    const int nh    = (t >> 6) & 1;
    const int l     = t & 63;
    const int n     = nh * 16 + (l & 15);
    const int g     = n >> 3, jj = n & 7;
    const int row   = g * SS + strip * 8 + jj;
    const int k     = step * 32 + (l >> 4) * 8 + q4;

    f32x4 v = *(const f32x4*)(W + (size_t)row * Kin + k);
    short4v hi, lo;
    #pragma unroll
    for (int q = 0; q < 4; ++q) {
        unsigned short hb = f2bf(v[q]);
        hi[q] = (short)hb; lo[q] = (short)f2bf(v[q] - bf2f(hb));
    }
    const size_t bHi = ((((size_t)strip * 2 + 0) * nst32 + step) * 2 + nh) * 512 + (size_t)l * 8 + q4;
    const size_t bLo = ((((size_t)strip * 2 + 1) * nst32 + step) * 2 + nh) * 512 + (size_t)l * 8 + q4;
    *(short4v*)(Wr + bHi) = hi;
    *(short4v*)(Wr + bLo) = lo;
}

// ---------------------------------------------------------------------------
// Adaptor: Y[1024][512] = A[1024][768] @ Wa[512][768]^T + ba, 3-pass MFMA.
// ---------------------------------------------------------------------------
__global__ __launch_bounds__(512) void adaptor_mfma(
    const unsigned short* __restrict__ Ahi, const unsigned short* __restrict__ Alo,
    const float* __restrict__ Wa, const float* __restrict__ ba,
    float* __restrict__ Y)
{
    const int tid  = threadIdx.x;
    const int lane = tid & 63;
    const int w    = tid >> 6;
    const int n0   = blockIdx.x * 16;
    const int r0   = blockIdx.y * 256 + w * 32;
    const int l15  = lane & 15;
    const int lk8  = (lane >> 4) * 8;

    f32x4 acc[2] = {{0,0,0,0},{0,0,0,0}};
    const float* Wrow = Wa + (size_t)(n0 + l15) * OUTD + lk8;
    for (int kb = 0; kb < OUTD; kb += 32) {
        f32x4 wv0 = *(const f32x4*)(Wrow + kb);
        f32x4 wv1 = *(const f32x4*)(Wrow + kb + 4);
        short8 whi, wlo;
        #pragma unroll
        for (int q = 0; q < 4; ++q) {
            unsigned short hb = f2bf(wv0[q]);
            whi[q] = (short)hb; wlo[q] = (short)f2bf(wv0[q] - bf2f(hb));
            unsigned short hb2 = f2bf(wv1[q]);
            whi[4+q] = (short)hb2; wlo[4+q] = (short)f2bf(wv1[q] - bf2f(hb2));
        }
        #pragma unroll
        for (int m = 0; m < 2; ++m) {
            const int r = r0 + m * 16 + l15;
            short8 ahi = *(const short8*)(Ahi + (size_t)r * OUTD + kb + lk8);
            short8 alo = *(const short8*)(Alo + (size_t)r * OUTD + kb + lk8);
            acc[m] = __builtin_amdgcn_mfma_f32_16x16x32_bf16(ahi, whi, acc[m], 0, 0, 0);
            acc[m] = __builtin_amdgcn_mfma_f32_16x16x32_bf16(alo, whi, acc[m], 0, 0, 0);
            acc[m] = __builtin_amdgcn_mfma_f32_16x16x32_bf16(ahi, wlo, acc[m], 0, 0, 0);
        }
    }
    const int c  = lane & 15;
    const int r4 = (lane >> 4) * 4;
    const float bb = ba[n0 + c];
    #pragma unroll
    for (int m = 0; m < 2; ++m)
        #pragma unroll
        for (int i = 0; i < 4; ++i)
            Y[(size_t)(r0 + m * 16 + r4 + i) * DOUT + n0 + c] = acc[m][i] + bb;
}

// ---------------------------------------------------------------------------
__global__ __launch_bounds__(256) void prep_split(
    const float* __restrict__ in, unsigned short* __restrict__ hi,
    unsigned short* __restrict__ lo, int n4)
{
    int i = blockIdx.x * 256 + threadIdx.x;
    if (i < n4) {
        f32x4 v = *(const f32x4*)(in + (size_t)i * 4);
        short4v sh, sl;
        #pragma unroll
        for (int j = 0; j < 4; ++j) {
            unsigned short hb = f2bf(v[j]);
            sh[j] = (short)hb; sl[j] = (short)f2bf(v[j] - bf2f(hb));
        }
        *(short4v*)(hi + (size_t)i * 4) = sh;
        *(short4v*)(lo + (size_t)i * 4) = sl;
    }
}

// ---------------------------------------------------------------------------
extern "C" void kernel_launch(void* const* d_in, const int* in_sizes, int n_in,
                              void* d_out, int out_size, void* d_ws, size_t ws_size,
                              hipStream_t stream)
{
    const float* x  = (const float*)d_in[0];
    const float* Wl[4] = {(const float*)d_in[1], (const float*)d_in[3],
                          (const float*)d_in[5], (const float*)d_in[7]};
    const float* bl[4] = {(const float*)d_in[2], (const float*)d_in[4],
                          (const float*)d_in[6], (const float*)d_in[8]};
    const float* Wa = (const float*)d_in[9];
    const float* ba = (const float*)d_in[10];
    float* out = (float*)d_out;

    // ---- workspace carve-up ----
    char* p = (char*)d_ws;
    auto take = [&](size_t bytes) { void* q = p; p += (bytes + 255) & ~(size_t)255; return q; };
    const size_t NX = (size_t)TT * BB * DIN;
    const size_t NH = (size_t)BB * HH;
    const size_t NC = (size_t)BB * SS;
    const size_t NO = (size_t)BB * OUTD;
    unsigned short* xHi = (unsigned short*)take(NX * 2);
    unsigned short* xLo = (unsigned short*)take(NX * 2);
    unsigned short* hHi = (unsigned short*)take(4 * TT * NH * 2);
    unsigned short* hLo = (unsigned short*)take(4 * TT * NH * 2);
    float*          cB  = (float*)take(4 * TT * NC * 4);
    unsigned short* oHi[4], *oLo[4];
    for (int l = 0; l < 4; ++l) {
        oHi[l] = (unsigned short*)take(TT * NO * 2);
        oLo[l] = (unsigned short*)take(TT * NO * 2);
    }
    float* o1F = (float*)take(TT * NO * 4);
    unsigned short* Wr[4];
    const int Kus[4] = {DIN, OUTD, OUTD, OUTD};
    const int dil[4] = {1, 2, 4, 8};
    int Kins[4], nst32s[4];
    for (int l = 0; l < 4; ++l) {
        Kins[l]   = Kus[l] + 2 * HH;
        nst32s[l] = Kins[l] / 32;
        Wr[l] = (unsigned short*)take((size_t)4 * SS * Kins[l] * 2 * 2);
    }

    // ---- prep ----
    hipLaunchKernelGGL(prep_split, dim3((NX / 4 + 255) / 256), dim3(256), 0, stream,
                       x, xHi, xLo, (int)(NX / 4));
    for (int l = 0; l < 4; ++l)
        hipLaunchKernelGGL(prep_reorderW, dim3(128, nst32s[l]), dim3(256), 0, stream,
                           Wl[l], Kins[l], nst32s[l], Wr[l]);

    // ---- wavefront: step s runs all cells (l, t=s-l) ----
    for (int s = 0; s <= TT - 1 + 3; ++s) {
        StepArgs sa;
        int n = 0;
        for (int l = 0; l < 4; ++l) {
            const int t = s - l;
            if (t < 0 || t >= TT) continue;
            CellDesc& d = sa.c[n++];
            const int Ku = Kus[l];
            const int prev_ok    = (t > 0);
            const int delayed_ok = (t >= dil[l]);
            const int tm1 = prev_ok ? t - 1 : 0;
            const int td  = delayed_ok ? t - dil[l] : tm1;
            const unsigned short* uHiL = (l == 0) ? xHi : oHi[l - 1];
            const unsigned short* uLoL = (l == 0) ? xLo : oLo[l - 1];
            unsigned short* hHl = hHi + (size_t)l * TT * NH;
            unsigned short* hLl = hLo + (size_t)l * TT * NH;
            float* cL = cB + (size_t)l * TT * NC;

            d.Wr   = Wr[l];
            d.bias = bl[l];
            d.uHi = uHiL + (size_t)t * BB * Ku;
            d.uLo = uLoL + (size_t)t * BB * Ku;
            d.hPrevHi = hHl + (size_t)tm1 * NH;
            d.hPrevLo = hLl + (size_t)tm1 * NH;
            d.hDelHi  = hHl + (size_t)td  * NH;
            d.hDelLo  = hLl + (size_t)td  * NH;
            d.cPrev = cL + (size_t)tm1 * NC;
            d.cDel  = cL + (size_t)td  * NC;
            d.cOut  = cL + (size_t)t   * NC;
            d.outHi = oHi[l] + (size_t)t * NO;
            d.outLo = oLo[l] + (size_t)t * NO;
            d.f32out = (l == 1) ? (o1F + (size_t)t * NO) : nullptr;
            d.resid  = (l == 3) ? (o1F + (size_t)t * NO) : nullptr;
            d.hHi = hHl + (size_t)t * NH;
            d.hLo = hLl + (size_t)t * NH;
            d.Ku = Ku; d.Kin = Kins[l];
            d.prev_ok = prev_ok; d.delayed_ok = delayed_ok;
            d.nst32 = nst32s[l]; d.pad = 0;
        }
        hipLaunchKernelGGL(cell_wave, dim3(n * 128), dim3(256), 0, stream, sa);
    }

    hipLaunchKernelGGL(adaptor_mfma, dim3(DOUT / 16, 4), dim3(512), 0, stream,
                       oHi[3], oLo[3], Wa, ba, out);
}

// Round 12
// 405.345 us; speedup vs baseline: 1.0865x; 1.0865x over previous
//
// fp16-W single-plane 2-pass variant (W stream halved; W-byte-bound per r8/r11 null).
#include <hip/hip_runtime.h>

#define BB   64
#define SS   1024
#define HH   256
#define OUTD 768
#define TT   16
#define DOUT 512
#define DIN  512

typedef __attribute__((ext_vector_type(8))) _Float16 half8;
typedef __attribute__((ext_vector_type(4))) float f32x4;
typedef __attribute__((ext_vector_type(4))) unsigned short us4;

__device__ __forceinline__ unsigned short f2h(float f) {
    _Float16 h = (_Float16)f;
    return __builtin_bit_cast(unsigned short, h);
}
__device__ __forceinline__ float h2f(unsigned short u) {
    return (float)__builtin_bit_cast(_Float16, u);
}

// ---------------------------------------------------------------------------
struct CellDesc {
    const unsigned short* Wr;        // fp16 [strip128][step32][nh2][lane64][8]
    const float* bias;
    const unsigned short *uHi, *uLo;           // fp16 planes
    const unsigned short *hPrevHi, *hPrevLo, *hDelHi, *hDelLo;
    const float *cPrev, *cDel;
    float* cOut;
    unsigned short *outHi, *outLo;
    float* f32out;
    const float* resid;
    unsigned short *hHi, *hLo;
    int Ku, Kin, prev_ok, delayed_ok, nst32, pad;
};
struct StepArgs { CellDesc c[4]; };

// ---------------------------------------------------------------------------
// Tiled wavefront cell kernel. grid = nCells*128 blocks x 256 thr (4 waves).
// Block (cell, strip): output tile = 64 rows x (8 state cols x 4 gates = 32 n).
// Waves (wm 2 x wh 2): wave = 32 rows x 16 n-cols, 2 m-frags.
// W: single fp16 plane. A: fp16 hi+lo. 2 MFMA passes (w*ahi + w*alo).
// K-loop: BK=64/step, A+W double-buffered in LDS, 1 barrier/step.
// ---------------------------------------------------------------------------
__global__ __launch_bounds__(256, 2) void cell_wave(StepArgs sa)
{
    __shared__ unsigned short Alds[2][2 * 64 * 72];   // [buf][pl*4608 + row*72 + k]
    __shared__ unsigned short Wlds[2][2048];          // [buf][((kk*2+nh)*64+l)*8]
    __shared__ float Csum[32 * 68];                   // [n][row]

    const int cellIdx = blockIdx.x >> 7;
    const int strip   = blockIdx.x & 127;
    const CellDesc& a = sa.c[cellIdx];

    const int tid  = threadIdx.x;
    const int lane = tid & 63;
    const int w    = tid >> 6;        // 0..3
    const int wm   = w >> 1;          // row half
    const int wh   = w & 1;           // n half
    const int l15  = lane & 15;
    const int lk8  = (lane >> 4) * 8;

    const int Ku    = a.Ku;
    const int nst32 = a.nst32;
    const int nst64 = (a.prev_ok ? a.Kin : a.Ku) >> 6;

    // staging maps (constant per thread): tid = wkk*128 + wnh*64 + wl
    f32x4 rA[2][2], rW;
    auto stageLoad = [&](int S) {
        const int kb = S * 64;
        const unsigned short *sHi, *sLo; int stride, koff;
        if (kb < Ku)           { sHi = a.uHi;     sLo = a.uLo;     stride = Ku; koff = kb; }
        else if (kb < Ku + HH) { sHi = a.hPrevHi; sLo = a.hPrevLo; stride = HH; koff = kb - Ku; }
        else                   { sHi = a.hDelHi;  sLo = a.hDelLo;  stride = HH; koff = kb - Ku - HH; }
        #pragma unroll
        for (int i = 0; i < 2; ++i) {
            const int e = i * 256 + tid;
            const int row = e >> 3, oct = e & 7;
            rA[0][i] = *(const f32x4*)(sHi + (size_t)row * stride + koff + oct * 8);
            rA[1][i] = *(const f32x4*)(sLo + (size_t)row * stride + koff + oct * 8);
        }
        // W: step32 index = 2S + wkk, nh = wnh, lane = wl -> 16B per thread
        const int wkk = tid >> 7, wnh = (tid >> 6) & 1, wl = tid & 63;
        const size_t wb = ((((size_t)strip * nst32 + (2 * S + wkk)) * 2 + wnh) * 64
                           + (size_t)wl) * 8;
        rW = *(const f32x4*)(a.Wr + wb);
    };
    auto stageWrite = [&](int nb) {
        #pragma unroll
        for (int i = 0; i < 2; ++i) {
            const int e = i * 256 + tid;
            const int row = e >> 3, oct = e & 7;
            *(f32x4*)&Alds[nb][row * 72 + oct * 8]        = rA[0][i];
            *(f32x4*)&Alds[nb][4608 + row * 72 + oct * 8] = rA[1][i];
        }
        *(f32x4*)&Wlds[nb][tid * 8] = rW;
    };

    f32x4 acc[2] = {{0,0,0,0},{0,0,0,0}};

    stageLoad(0);
    stageWrite(0);
    __syncthreads();

    int cur = 0;
    for (int S = 0; S < nst64; ++S) {
        const bool more = (S + 1 < nst64);
        if (more) stageLoad(S + 1);

        #pragma unroll
        for (int kk = 0; kk < 2; ++kk) {
            half8 wv = *(const half8*)&Wlds[cur][((kk * 2 + wh) * 64 + lane) * 8];
            #pragma unroll
            for (int mm = 0; mm < 2; ++mm) {
                const int row = wm * 32 + mm * 16 + l15;
                half8 ahi = *(const half8*)&Alds[cur][row * 72 + kk * 32 + lk8];
                half8 alo = *(const half8*)&Alds[cur][4608 + row * 72 + kk * 32 + lk8];
                acc[mm] = __builtin_amdgcn_mfma_f32_16x16x32_f16(ahi, wv, acc[mm], 0, 0, 0);
                acc[mm] = __builtin_amdgcn_mfma_f32_16x16x32_f16(alo, wv, acc[mm], 0, 0, 0);
            }
        }
        if (more) stageWrite(cur ^ 1);
        __syncthreads();
        cur ^= 1;
    }

    // C frags -> Csum  (col c=lane&15 -> n = wh*16+c; row = wm*32+mm*16+(lane>>4)*4+i)
    {
        const int c  = lane & 15;
        const int r4 = (lane >> 4) * 4;
        #pragma unroll
        for (int mm = 0; mm < 2; ++mm)
            *(f32x4*)&Csum[(wh * 16 + c) * 68 + wm * 32 + mm * 16 + r4] = acc[mm];
    }
    __syncthreads();

    // block-local LSTM epilogue: 64 rows x 8 state cols, 2 per thread; n = g*8+jj
    #pragma unroll
    for (int e2 = 0; e2 < 2; ++e2) {
        const int idx = tid + e2 * 256;
        const int r   = idx >> 3;
        const int jj  = idx & 7;
        const int j   = strip * 8 + jj;
        float g0 = Csum[(0  + jj) * 68 + r] + a.bias[j];
        float g1 = Csum[(8  + jj) * 68 + r] + a.bias[SS + j];
        float g2 = Csum[(16 + jj) * 68 + r] + a.bias[2 * SS + j];
        float g3 = Csum[(24 + jj) * 68 + r] + a.bias[3 * SS + j];

        float f  = 1.f / (1.f + __expf(-(g0 + 1.f)));
        float n  = tanhf(g1);
        float av = 1.f / (1.f + __expf(-g2));
        float o  = 1.f / (1.f + __expf(-g3));

        float pC = a.prev_ok ? a.cPrev[(size_t)r * SS + j] : 0.f;
        float dC = a.delayed_ok ? a.cDel[(size_t)r * SS + j] : pC;
        float wC = a.delayed_ok ? (av * pC + (1.f - av) * dC) : pC;
        float nf = a.prev_ok ? (f * wC + (1.f - f) * n) : n;
        float wh2 = o * nf;

        a.cOut[(size_t)r * SS + j] = nf;

        if (j < OUTD) {
            float v = wh2;
            const size_t oidx = (size_t)r * OUTD + j;
            if (a.resid)  v += a.resid[oidx];
            if (a.f32out) a.f32out[oidx] = v;
            unsigned short hb = f2h(v);
            a.outHi[oidx] = hb;
            a.outLo[oidx] = f2h(v - h2f(hb));
        } else {
            const int jo = j - OUTD;
            const size_t hidx = (size_t)r * HH + jo;
            unsigned short hb = f2h(wh2);
            a.hHi[hidx] = hb;
            a.hLo[hidx] = f2h(wh2 - h2f(hb));
        }
    }
}

// ---------------------------------------------------------------------------
// W reorder: fp32 [4096][Kin] -> single fp16 plane, fragment-linear:
// [strip128][step32][nh2][lane64][8]
// n = nh*16 + (l&15); g = n>>3; jj = n&7; W row = g*1024 + strip*8 + jj;
// k = step*32 + (l>>4)*8 + q4(+q).
// ---------------------------------------------------------------------------
__global__ __launch_bounds__(256) void prep_reorderW(
    const float* __restrict__ W, int Kin, int nst32,
    unsigned short* __restrict__ Wr)
{
    const int strip = blockIdx.x;     // 0..127
    const int step  = blockIdx.y;     // 0..nst32-1
    const int t     = threadIdx.x;
    const int q4    = (t >> 7) * 4;   // 0 or 4
    const int nh    = (t >> 6) & 1;
    const int l     = t & 63;
    const int n     = nh * 16 + (l & 15);
    const int g     = n >> 3, jj = n & 7;
    const int row   = g * SS + strip * 8 + jj;
    const int k     = step * 32 + (l >> 4) * 8 + q4;

    f32x4 v = *(const f32x4*)(W + (size_t)row * Kin + k);
    us4 hv;
    #pragma unroll
    for (int q = 0; q < 4; ++q) hv[q] = f2h(v[q]);
    const size_t b = ((((size_t)strip * nst32 + step) * 2 + nh) * 64 + (size_t)l) * 8 + q4;
    *(us4*)(Wr + b) = hv;
}

// ---------------------------------------------------------------------------
// Adaptor: Y[1024][512] = A[1024][768] @ Wa[512][768]^T + ba, 2-pass fp16 MFMA.
// ---------------------------------------------------------------------------
__global__ __launch_bounds__(512) void adaptor_mfma(
    const unsigned short* __restrict__ Ahi, const unsigned short* __restrict__ Alo,
    const float* __restrict__ Wa, const float* __restrict__ ba,
    float* __restrict__ Y)
{
    const int tid  = threadIdx.x;
    const int lane = tid & 63;
    const int w    = tid >> 6;
    const int n0   = blockIdx.x * 16;
    const int r0   = blockIdx.y * 256 + w * 32;
    const int l15  = lane & 15;
    const int lk8  = (lane >> 4) * 8;

    f32x4 acc[2] = {{0,0,0,0},{0,0,0,0}};
    const float* Wrow = Wa + (size_t)(n0 + l15) * OUTD + lk8;
    for (int kb = 0; kb < OUTD; kb += 32) {
        f32x4 wv0 = *(const f32x4*)(Wrow + kb);
        f32x4 wv1 = *(const f32x4*)(Wrow + kb + 4);
        half8 wv;
        #pragma unroll
        for (int q = 0; q < 4; ++q) {
            wv[q]     = __builtin_bit_cast(_Float16, f2h(wv0[q]));
            wv[4 + q] = __builtin_bit_cast(_Float16, f2h(wv1[q]));
        }
        #pragma unroll
        for (int m = 0; m < 2; ++m) {
            const int r = r0 + m * 16 + l15;
            half8 ahi = *(const half8*)(Ahi + (size_t)r * OUTD + kb + lk8);
            half8 alo = *(const half8*)(Alo + (size_t)r * OUTD + kb + lk8);
            acc[m] = __builtin_amdgcn_mfma_f32_16x16x32_f16(ahi, wv, acc[m], 0, 0, 0);
            acc[m] = __builtin_amdgcn_mfma_f32_16x16x32_f16(alo, wv, acc[m], 0, 0, 0);
        }
    }
    const int c  = lane & 15;
    const int r4 = (lane >> 4) * 4;
    const float bb = ba[n0 + c];
    #pragma unroll
    for (int m = 0; m < 2; ++m)
        #pragma unroll
        for (int i = 0; i < 4; ++i)
            Y[(size_t)(r0 + m * 16 + r4 + i) * DOUT + n0 + c] = acc[m][i] + bb;
}

// ---------------------------------------------------------------------------
__global__ __launch_bounds__(256) void prep_split(
    const float* __restrict__ in, unsigned short* __restrict__ hi,
    unsigned short* __restrict__ lo, int n4)
{
    int i = blockIdx.x * 256 + threadIdx.x;
    if (i < n4) {
        f32x4 v = *(const f32x4*)(in + (size_t)i * 4);
        us4 sh, sl;
        #pragma unroll
        for (int j = 0; j < 4; ++j) {
            unsigned short hb = f2h(v[j]);
            sh[j] = hb;
            sl[j] = f2h(v[j] - h2f(hb));
        }
        *(us4*)(hi + (size_t)i * 4) = sh;
        *(us4*)(lo + (size_t)i * 4) = sl;
    }
}

// ---------------------------------------------------------------------------
extern "C" void kernel_launch(void* const* d_in, const int* in_sizes, int n_in,
                              void* d_out, int out_size, void* d_ws, size_t ws_size,
                              hipStream_t stream)
{
    const float* x  = (const float*)d_in[0];
    const float* Wl[4] = {(const float*)d_in[1], (const float*)d_in[3],
                          (const float*)d_in[5], (const float*)d_in[7]};
    const float* bl[4] = {(const float*)d_in[2], (const float*)d_in[4],
                          (const float*)d_in[6], (const float*)d_in[8]};
    const float* Wa = (const float*)d_in[9];
    const float* ba = (const float*)d_in[10];
    float* out = (float*)d_out;

    // ---- workspace carve-up ----
    char* p = (char*)d_ws;
    auto take = [&](size_t bytes) { void* q = p; p += (bytes + 255) & ~(size_t)255; return q; };
    const size_t NX = (size_t)TT * BB * DIN;
    const size_t NH = (size_t)BB * HH;
    const size_t NC = (size_t)BB * SS;
    const size_t NO = (size_t)BB * OUTD;
    unsigned short* xHi = (unsigned short*)take(NX * 2);
    unsigned short* xLo = (unsigned short*)take(NX * 2);
    unsigned short* hHi = (unsigned short*)take(4 * TT * NH * 2);
    unsigned short* hLo = (unsigned short*)take(4 * TT * NH * 2);
    float*          cB  = (float*)take(4 * TT * NC * 4);
    unsigned short* oHi[4], *oLo[4];
    for (int l = 0; l < 4; ++l) {
        oHi[l] = (unsigned short*)take(TT * NO * 2);
        oLo[l] = (unsigned short*)take(TT * NO * 2);
    }
    float* o1F = (float*)take(TT * NO * 4);
    unsigned short* Wr[4];
    const int Kus[4] = {DIN, OUTD, OUTD, OUTD};
    const int dil[4] = {1, 2, 4, 8};
    int Kins[4], nst32s[4];
    for (int l = 0; l < 4; ++l) {
        Kins[l]   = Kus[l] + 2 * HH;
        nst32s[l] = Kins[l] / 32;
        Wr[l] = (unsigned short*)take((size_t)4 * SS * Kins[l] * 2);   // fp16 single plane
    }

    // ---- prep ----
    hipLaunchKernelGGL(prep_split, dim3((NX / 4 + 255) / 256), dim3(256), 0, stream,
                       x, xHi, xLo, (int)(NX / 4));
    for (int l = 0; l < 4; ++l)
        hipLaunchKernelGGL(prep_reorderW, dim3(128, nst32s[l]), dim3(256), 0, stream,
                           Wl[l], Kins[l], nst32s[l], Wr[l]);

    // ---- wavefront: step s runs all cells (l, t=s-l) ----
    for (int s = 0; s <= TT - 1 + 3; ++s) {
        StepArgs sa;
        int n = 0;
        for (int l = 0; l < 4; ++l) {
            const int t = s - l;
            if (t < 0 || t >= TT) continue;
            CellDesc& d = sa.c[n++];
            const int Ku = Kus[l];
            const int prev_ok    = (t > 0);
            const int delayed_ok = (t >= dil[l]);
            const int tm1 = prev_ok ? t - 1 : 0;
            const int td  = delayed_ok ? t - dil[l] : tm1;
            const unsigned short* uHiL = (l == 0) ? xHi : oHi[l - 1];
            const unsigned short* uLoL = (l == 0) ? xLo : oLo[l - 1];
            unsigned short* hHl = hHi + (size_t)l * TT * NH;
            unsigned short* hLl = hLo + (size_t)l * TT * NH;
            float* cL = cB + (size_t)l * TT * NC;

            d.Wr   = Wr[l];
            d.bias = bl[l];
            d.uHi = uHiL + (size_t)t * BB * Ku;
            d.uLo = uLoL + (size_t)t * BB * Ku;
            d.hPrevHi = hHl + (size_t)tm1 * NH;
            d.hPrevLo = hLl + (size_t)tm1 * NH;
            d.hDelHi  = hHl + (size_t)td  * NH;
            d.hDelLo  = hLl + (size_t)td  * NH;
            d.cPrev = cL + (size_t)tm1 * NC;
            d.cDel  = cL + (size_t)td  * NC;
            d.cOut  = cL + (size_t)t   * NC;
            d.outHi = oHi[l] + (size_t)t * NO;
            d.outLo = oLo[l] + (size_t)t * NO;
            d.f32out = (l == 1) ? (o1F + (size_t)t * NO) : nullptr;
            d.resid  = (l == 3) ? (o1F + (size_t)t * NO) : nullptr;
            d.hHi = hHl + (size_t)t * NH;
            d.hLo = hLl + (size_t)t * NH;
            d.Ku = Ku; d.Kin = Kins[l];
            d.prev_ok = prev_ok; d.delayed_ok = delayed_ok;
            d.nst32 = nst32s[l]; d.pad = 0;
        }
        hipLaunchKernelGGL(cell_wave, dim3(n * 128), dim3(256), 0, stream, sa);
    }

    hipLaunchKernelGGL(adaptor_mfma, dim3(DOUT / 16, 4), dim3(512), 0, stream,
                       oHi[3], oLo[3], Wa, ba, out);
}

// Round 13
// 280.149 us; speedup vs baseline: 1.5721x; 1.4469x over previous
//
// r13: A single fp16 plane (1-pass MFMA), BK=128 stages, fused W-reorder.
#include <hip/hip_runtime.h>

#define BB   64
#define SS   1024
#define HH   256
#define OUTD 768
#define TT   16
#define DOUT 512
#define DIN  512

typedef __attribute__((ext_vector_type(8))) _Float16 half8;
typedef __attribute__((ext_vector_type(4))) float f32x4;
typedef __attribute__((ext_vector_type(4))) unsigned short us4;

__device__ __forceinline__ unsigned short f2h(float f) {
    _Float16 h = (_Float16)f;
    return __builtin_bit_cast(unsigned short, h);
}
__device__ __forceinline__ float h2f(unsigned short u) {
    return (float)__builtin_bit_cast(_Float16, u);
}

// ---------------------------------------------------------------------------
struct CellDesc {
    const unsigned short* Wr;        // fp16 [strip128][step32][nh2][lane64][8]
    const float* bias;
    const unsigned short* uH;        // fp16 single plane
    const unsigned short *hPrevH, *hDelH;
    const float *cPrev, *cDel;
    float* cOut;
    unsigned short* outH;
    float* f32out;
    const float* resid;
    unsigned short* hH;
    int Ku, Kin, prev_ok, delayed_ok, nst32, pad;
};
struct StepArgs { CellDesc c[4]; };

// ---------------------------------------------------------------------------
// Tiled wavefront cell kernel. grid = nCells*128 blocks x 256 thr (4 waves).
// Block (cell, strip): output tile = 64 rows x (8 state cols x 4 gates = 32 n).
// Waves (wm 2 x wh 2): wave = 32 rows x 16 n-cols, 2 m-frags.
// fp16 x fp16 single-pass MFMA. BK=128 per stage (10 stages max, 10 barriers).
// A+W double-buffered in LDS; issue-early loads, write-late after compute.
// ---------------------------------------------------------------------------
__global__ __launch_bounds__(256, 2) void cell_wave(StepArgs sa)
{
    __shared__ unsigned short Alds[2][64 * 136];   // [buf][row*136 + k] (pitch +8)
    __shared__ unsigned short Wlds[2][4096];       // [buf][((kk*2+nh)*64+l)*8]
    __shared__ float Csum[32 * 68];                // [n][row]

    const int cellIdx = blockIdx.x >> 7;
    const int strip   = blockIdx.x & 127;
    const CellDesc& a = sa.c[cellIdx];

    const int tid  = threadIdx.x;
    const int lane = tid & 63;
    const int w    = tid >> 6;        // 0..3
    const int wm   = w >> 1;          // row half
    const int wh   = w & 1;           // n half
    const int l15  = lane & 15;
    const int lk8  = (lane >> 4) * 8;

    const int Ku     = a.Ku;
    const int nst32  = a.nst32;
    const int nst128 = (a.prev_ok ? a.Kin : a.Ku) >> 7;

    f32x4 rA[4], rW[2];
    auto stageLoad = [&](int S) {
        const int kb = S * 128;
        const unsigned short* src; int stride, koff;
        if (kb < Ku)           { src = a.uH;     stride = Ku; koff = kb; }
        else if (kb < Ku + HH) { src = a.hPrevH; stride = HH; koff = kb - Ku; }
        else                   { src = a.hDelH;  stride = HH; koff = kb - Ku - HH; }
        #pragma unroll
        for (int i = 0; i < 4; ++i) {
            const int e = i * 256 + tid;
            const int row = e >> 4, oct = e & 15;
            rA[i] = *(const f32x4*)(src + (size_t)row * stride + koff + oct * 8);
        }
        #pragma unroll
        for (int i = 0; i < 2; ++i) {
            const int c  = i * 256 + tid;             // 0..511 chunk id
            const int kk = c >> 7, nh = (c >> 6) & 1, l = c & 63;
            const size_t wb = ((((size_t)strip * nst32 + (4 * S + kk)) * 2 + nh) * 64
                               + (size_t)l) * 8;
            rW[i] = *(const f32x4*)(a.Wr + wb);
        }
    };
    auto stageWrite = [&](int nb) {
        #pragma unroll
        for (int i = 0; i < 4; ++i) {
            const int e = i * 256 + tid;
            const int row = e >> 4, oct = e & 15;
            *(f32x4*)&Alds[nb][row * 136 + oct * 8] = rA[i];
        }
        #pragma unroll
        for (int i = 0; i < 2; ++i)
            *(f32x4*)&Wlds[nb][(i * 256 + tid) * 8] = rW[i];
    };

    f32x4 acc[2] = {{0,0,0,0},{0,0,0,0}};

    stageLoad(0);
    stageWrite(0);
    __syncthreads();

    int cur = 0;
    for (int S = 0; S < nst128; ++S) {
        const bool more = (S + 1 < nst128);
        if (more) stageLoad(S + 1);

        #pragma unroll
        for (int kk = 0; kk < 4; ++kk) {
            half8 wv = *(const half8*)&Wlds[cur][((kk * 2 + wh) * 64 + lane) * 8];
            #pragma unroll
            for (int mm = 0; mm < 2; ++mm) {
                const int row = wm * 32 + mm * 16 + l15;
                half8 av = *(const half8*)&Alds[cur][row * 136 + kk * 32 + lk8];
                acc[mm] = __builtin_amdgcn_mfma_f32_16x16x32_f16(av, wv, acc[mm], 0, 0, 0);
            }
        }
        if (more) stageWrite(cur ^ 1);
        __syncthreads();
        cur ^= 1;
    }

    // C frags -> Csum  (col c=lane&15 -> n = wh*16+c; row = wm*32+mm*16+(lane>>4)*4+i)
    {
        const int c  = lane & 15;
        const int r4 = (lane >> 4) * 4;
        #pragma unroll
        for (int mm = 0; mm < 2; ++mm)
            *(f32x4*)&Csum[(wh * 16 + c) * 68 + wm * 32 + mm * 16 + r4] = acc[mm];
    }
    __syncthreads();

    // block-local LSTM epilogue: 64 rows x 8 state cols, 2 per thread; n = g*8+jj
    #pragma unroll
    for (int e2 = 0; e2 < 2; ++e2) {
        const int idx = tid + e2 * 256;
        const int r   = idx >> 3;
        const int jj  = idx & 7;
        const int j   = strip * 8 + jj;
        float g0 = Csum[(0  + jj) * 68 + r] + a.bias[j];
        float g1 = Csum[(8  + jj) * 68 + r] + a.bias[SS + j];
        float g2 = Csum[(16 + jj) * 68 + r] + a.bias[2 * SS + j];
        float g3 = Csum[(24 + jj) * 68 + r] + a.bias[3 * SS + j];

        float f  = 1.f / (1.f + __expf(-(g0 + 1.f)));
        float n  = tanhf(g1);
        float av = 1.f / (1.f + __expf(-g2));
        float o  = 1.f / (1.f + __expf(-g3));

        float pC = a.prev_ok ? a.cPrev[(size_t)r * SS + j] : 0.f;
        float dC = a.delayed_ok ? a.cDel[(size_t)r * SS + j] : pC;
        float wC = a.delayed_ok ? (av * pC + (1.f - av) * dC) : pC;
        float nf = a.prev_ok ? (f * wC + (1.f - f) * n) : n;
        float wh2 = o * nf;

        a.cOut[(size_t)r * SS + j] = nf;

        if (j < OUTD) {
            float v = wh2;
            const size_t oidx = (size_t)r * OUTD + j;
            if (a.resid)  v += a.resid[oidx];
            if (a.f32out) a.f32out[oidx] = v;
            a.outH[oidx] = f2h(v);
        } else {
            a.hH[(size_t)r * HH + (j - OUTD)] = f2h(wh2);
        }
    }
}

// ---------------------------------------------------------------------------
// Fused W reorder (all 4 layers): fp32 [4096][Kin] -> fp16 fragment-linear
// [strip128][step32][nh2][lane64][8].
// n = nh*16 + (l&15); g = n>>3; jj = n&7; W row = g*1024 + strip*8 + jj;
// k = step*32 + (l>>4)*8 + q4.
// ---------------------------------------------------------------------------
struct ReorderArgs {
    const float* W[4];
    unsigned short* Wr[4];
    int Kin[4];
    int nst32[4];
};
__global__ __launch_bounds__(256) void prep_reorderW(ReorderArgs ra)
{
    const int lay   = blockIdx.z;
    const int strip = blockIdx.x;     // 0..127
    const int step  = blockIdx.y;     // 0..39 (guarded)
    if (step >= ra.nst32[lay]) return;
    const int Kin   = ra.Kin[lay];
    const int t     = threadIdx.x;
    const int q4    = (t >> 7) * 4;   // 0 or 4
    const int nh    = (t >> 6) & 1;
    const int l     = t & 63;
    const int n     = nh * 16 + (l & 15);
    const int g     = n >> 3, jj = n & 7;
    const int row   = g * SS + strip * 8 + jj;
    const int k     = step * 32 + (l >> 4) * 8 + q4;

    f32x4 v = *(const f32x4*)(ra.W[lay] + (size_t)row * Kin + k);
    us4 hv;
    #pragma unroll
    for (int q = 0; q < 4; ++q) hv[q] = f2h(v[q]);
    const size_t b = ((((size_t)strip * ra.nst32[lay] + step) * 2 + nh) * 64
                      + (size_t)l) * 8 + q4;
    *(us4*)(ra.Wr[lay] + b) = hv;
}

// ---------------------------------------------------------------------------
// Adaptor: Y[1024][512] = A[1024][768] @ Wa[512][768]^T + ba, 1-pass fp16 MFMA.
// ---------------------------------------------------------------------------
__global__ __launch_bounds__(512) void adaptor_mfma(
    const unsigned short* __restrict__ Ah,
    const float* __restrict__ Wa, const float* __restrict__ ba,
    float* __restrict__ Y)
{
    const int tid  = threadIdx.x;
    const int lane = tid & 63;
    const int w    = tid >> 6;
    const int n0   = blockIdx.x * 16;
    const int r0   = blockIdx.y * 256 + w * 32;
    const int l15  = lane & 15;
    const int lk8  = (lane >> 4) * 8;

    f32x4 acc[2] = {{0,0,0,0},{0,0,0,0}};
    const float* Wrow = Wa + (size_t)(n0 + l15) * OUTD + lk8;
    for (int kb = 0; kb < OUTD; kb += 32) {
        f32x4 wv0 = *(const f32x4*)(Wrow + kb);
        f32x4 wv1 = *(const f32x4*)(Wrow + kb + 4);
        half8 wv;
        #pragma unroll
        for (int q = 0; q < 4; ++q) {
            wv[q]     = __builtin_bit_cast(_Float16, f2h(wv0[q]));
            wv[4 + q] = __builtin_bit_cast(_Float16, f2h(wv1[q]));
        }
        #pragma unroll
        for (int m = 0; m < 2; ++m) {
            const int r = r0 + m * 16 + l15;
            half8 av = *(const half8*)(Ah + (size_t)r * OUTD + kb + lk8);
            acc[m] = __builtin_amdgcn_mfma_f32_16x16x32_f16(av, wv, acc[m], 0, 0, 0);
        }
    }
    const int c  = lane & 15;
    const int r4 = (lane >> 4) * 4;
    const float bb = ba[n0 + c];
    #pragma unroll
    for (int m = 0; m < 2; ++m)
        #pragma unroll
        for (int i = 0; i < 4; ++i)
            Y[(size_t)(r0 + m * 16 + r4 + i) * DOUT + n0 + c] = acc[m][i] + bb;
}

// ---------------------------------------------------------------------------
__global__ __launch_bounds__(256) void prep_split(
    const float* __restrict__ in, unsigned short* __restrict__ hi, int n4)
{
    int i = blockIdx.x * 256 + threadIdx.x;
    if (i < n4) {
        f32x4 v = *(const f32x4*)(in + (size_t)i * 4);
        us4 sh;
        #pragma unroll
        for (int j = 0; j < 4; ++j) sh[j] = f2h(v[j]);
        *(us4*)(hi + (size_t)i * 4) = sh;
    }
}

// ---------------------------------------------------------------------------
extern "C" void kernel_launch(void* const* d_in, const int* in_sizes, int n_in,
                              void* d_out, int out_size, void* d_ws, size_t ws_size,
                              hipStream_t stream)
{
    const float* x  = (const float*)d_in[0];
    const float* Wl[4] = {(const float*)d_in[1], (const float*)d_in[3],
                          (const float*)d_in[5], (const float*)d_in[7]};
    const float* bl[4] = {(const float*)d_in[2], (const float*)d_in[4],
                          (const float*)d_in[6], (const float*)d_in[8]};
    const float* Wa = (const float*)d_in[9];
    const float* ba = (const float*)d_in[10];
    float* out = (float*)d_out;

    // ---- workspace carve-up ----
    char* p = (char*)d_ws;
    auto take = [&](size_t bytes) { void* q = p; p += (bytes + 255) & ~(size_t)255; return q; };
    const size_t NX = (size_t)TT * BB * DIN;
    const size_t NH = (size_t)BB * HH;
    const size_t NC = (size_t)BB * SS;
    const size_t NO = (size_t)BB * OUTD;
    unsigned short* xH = (unsigned short*)take(NX * 2);
    unsigned short* hB = (unsigned short*)take(4 * TT * NH * 2);
    float*          cB = (float*)take(4 * TT * NC * 4);
    unsigned short* oH[4];
    for (int l = 0; l < 4; ++l) oH[l] = (unsigned short*)take(TT * NO * 2);
    float* o1F = (float*)take(TT * NO * 4);
    unsigned short* Wr[4];
    const int Kus[4] = {DIN, OUTD, OUTD, OUTD};
    const int dil[4] = {1, 2, 4, 8};
    int Kins[4], nst32s[4];
    for (int l = 0; l < 4; ++l) {
        Kins[l]   = Kus[l] + 2 * HH;
        nst32s[l] = Kins[l] / 32;
        Wr[l] = (unsigned short*)take((size_t)4 * SS * Kins[l] * 2);
    }

    // ---- prep: input fp16 cast + fused W reorder ----
    hipLaunchKernelGGL(prep_split, dim3((NX / 4 + 255) / 256), dim3(256), 0, stream,
                       x, xH, (int)(NX / 4));
    {
        ReorderArgs ra;
        int maxst = 0;
        for (int l = 0; l < 4; ++l) {
            ra.W[l] = Wl[l]; ra.Wr[l] = Wr[l];
            ra.Kin[l] = Kins[l]; ra.nst32[l] = nst32s[l];
            if (nst32s[l] > maxst) maxst = nst32s[l];
        }
        hipLaunchKernelGGL(prep_reorderW, dim3(128, maxst, 4), dim3(256), 0, stream, ra);
    }

    // ---- wavefront: step s runs all cells (l, t=s-l) ----
    for (int s = 0; s <= TT - 1 + 3; ++s) {
        StepArgs sa;
        int n = 0;
        for (int l = 0; l < 4; ++l) {
            const int t = s - l;
            if (t < 0 || t >= TT) continue;
            CellDesc& d = sa.c[n++];
            const int Ku = Kus[l];
            const int prev_ok    = (t > 0);
            const int delayed_ok = (t >= dil[l]);
            const int tm1 = prev_ok ? t - 1 : 0;
            const int td  = delayed_ok ? t - dil[l] : tm1;
            const unsigned short* uHL = (l == 0) ? xH : oH[l - 1];
            unsigned short* hHl = hB + (size_t)l * TT * NH;
            float* cL = cB + (size_t)l * TT * NC;

            d.Wr   = Wr[l];
            d.bias = bl[l];
            d.uH = uHL + (size_t)t * BB * Ku;
            d.hPrevH = hHl + (size_t)tm1 * NH;
            d.hDelH  = hHl + (size_t)td  * NH;
            d.cPrev = cL + (size_t)tm1 * NC;
            d.cDel  = cL + (size_t)td  * NC;
            d.cOut  = cL + (size_t)t   * NC;
            d.outH  = oH[l] + (size_t)t * NO;
            d.f32out = (l == 1) ? (o1F + (size_t)t * NO) : nullptr;
            d.resid  = (l == 3) ? (o1F + (size_t)t * NO) : nullptr;
            d.hH = hHl + (size_t)t * NH;
            d.Ku = Ku; d.Kin = Kins[l];
            d.prev_ok = prev_ok; d.delayed_ok = delayed_ok;
            d.nst32 = nst32s[l]; d.pad = 0;
        }
        hipLaunchKernelGGL(cell_wave, dim3(n * 128), dim3(256), 0, stream, sa);
    }

    hipLaunchKernelGGL(adaptor_mfma, dim3(DOUT / 16, 4), dim3(512), 0, stream,
                       oH[3], Wa, ba, out);
}